// Round 6
// baseline (1389.526 us; speedup 1.0000x reference)
//
#include <hip/hip_runtime.h>
#include <stdint.h>

#define N_ 2048
#define D_ 128
#define B_ 8
#define NT 16            // N_/128
#define NPAIRS 136       // NT*(NT+1)/2 upper-triangle tile pairs
#define NBIN2 65536

typedef __attribute__((ext_vector_type(8))) short short8;
typedef __attribute__((ext_vector_type(4))) float f32x4;

// ws layout (bytes)
#define OFF_ACCUM 0
#define OFF_RU    64
#define OFF_THR   256
#define OFF_HIST  512                            // 16*65536*4 = 4 MB
#define OFF_END   (512 + (size_t)16*NBIN2*4)
#define OFF_H     OFF_END                        // 16 panels * 2048*128 * 2B = 8 MB
#define OFF_L     (OFF_H + (size_t)8388608)
#define NEED      (OFF_L + (size_t)8388608)

// f32 -> bf16 bits, round-to-nearest-even (finite inputs only)
__device__ __forceinline__ uint32_t bf16_rne(float x) {
    uint32_t u = __float_as_uint(x);
    return (u + 0x7fffu + ((u >> 16) & 1u)) >> 16;
}

// Fragment-major panel layout: panel p (2048 rows x 128 k) stored as
// [128 row-tiles rt][4 k-tiles kt] fragments of 1KB; within a fragment,
// lane l = (r&15) + ((k>>3)&3)*16 owns 16B (8 bf16) at l*16.
// A wave loads an MFMA operand as one dwordx4 at frag_base + lane*16.

// 128x128 tile (ti,tj) of sim, direct-from-global fragments, software-
// pipelined (kt+1 operands loaded before kt's MFMAs). FULL: hh+hl+lh split
// (f32-accurate); !FULL: hh only (hist estimation).
template<bool FULL>
__device__ __forceinline__ void gemm_tile(const ushort* __restrict__ Hp,
        const ushort* __restrict__ Lp, int ti, int tj, f32x4 acc[4][4], int t)
{
    const int lane = t & 63;
    const int wv = t >> 6, wr = wv >> 1, wc = wv & 1;
    const ushort* AH = Hp + (size_t)(ti*8 + wr*4)*2048 + (size_t)lane*8;
    const ushort* BH = Hp + (size_t)(tj*8 + wc*4)*2048 + (size_t)lane*8;
    const ushort* AL = Lp + (size_t)(ti*8 + wr*4)*2048 + (size_t)lane*8;
    const ushort* BL = Lp + (size_t)(tj*8 + wc*4)*2048 + (size_t)lane*8;

    short8 ah[2][4], bh[2][4], al[2][4], bl[2][4];
    #pragma unroll
    for (int mm = 0; mm < 4; ++mm) {
        ah[0][mm] = *(const short8*)&AH[mm*2048];
        bh[0][mm] = *(const short8*)&BH[mm*2048];
        if (FULL) {
            al[0][mm] = *(const short8*)&AL[mm*2048];
            bl[0][mm] = *(const short8*)&BL[mm*2048];
        }
    }
    #pragma unroll
    for (int mm = 0; mm < 4; ++mm)
        #pragma unroll
        for (int nn = 0; nn < 4; ++nn)
            acc[mm][nn] = f32x4{0.f, 0.f, 0.f, 0.f};

    #pragma unroll
    for (int kt = 0; kt < 4; ++kt) {
        const int cur = kt & 1, nxt = cur ^ 1;
        if (kt < 3) {
            #pragma unroll
            for (int mm = 0; mm < 4; ++mm) {
                ah[nxt][mm] = *(const short8*)&AH[mm*2048 + (kt+1)*512];
                bh[nxt][mm] = *(const short8*)&BH[mm*2048 + (kt+1)*512];
                if (FULL) {
                    al[nxt][mm] = *(const short8*)&AL[mm*2048 + (kt+1)*512];
                    bl[nxt][mm] = *(const short8*)&BL[mm*2048 + (kt+1)*512];
                }
            }
        }
        #pragma unroll
        for (int mm = 0; mm < 4; ++mm)
            #pragma unroll
            for (int nn = 0; nn < 4; ++nn) {
                acc[mm][nn] = __builtin_amdgcn_mfma_f32_16x16x32_bf16(ah[cur][mm], bh[cur][nn], acc[mm][nn], 0, 0, 0);
                if (FULL) {
                    acc[mm][nn] = __builtin_amdgcn_mfma_f32_16x16x32_bf16(ah[cur][mm], bl[cur][nn], acc[mm][nn], 0, 0, 0);
                    acc[mm][nn] = __builtin_amdgcn_mfma_f32_16x16x32_bf16(al[cur][mm], bh[cur][nn], acc[mm][nn], 0, 0, 0);
                }
            }
    }
}

// f32 -> (hi,lo) bf16 fragment-major panels + fused per-pair max row-norm^2
__global__ __launch_bounds__(256) void convert_kernel(
    const float* __restrict__ Xin, const float* __restrict__ Xtg,
    ushort* __restrict__ H, ushort* __restrict__ L, uint32_t* __restrict__ Ru)
{
    const int t = threadIdx.x;
    const int m = blockIdx.y;
    const float* X = m ? Xtg : Xin;
    const size_t e8 = (size_t)blockIdx.x * 256 + t;
    const size_t idx = e8 * 8;
    const int b = (int)(e8 >> 15);
    const int r = (int)((idx >> 7) & 2047);
    const int k = (int)(idx & 127);

    float4 v0 = *(const float4*)&X[idx];
    float4 v1 = *(const float4*)&X[idx + 4];
    ushort h8[8], l8[8];
    float vv[8] = {v0.x, v0.y, v0.z, v0.w, v1.x, v1.y, v1.z, v1.w};
    float s = 0.f;
    #pragma unroll
    for (int j = 0; j < 8; ++j) {
        uint32_t h = bf16_rne(vv[j]);
        h8[j] = (ushort)h;
        l8[j] = (ushort)bf16_rne(vv[j] - __uint_as_float(h << 16));
        s += vv[j] * vv[j];
    }
    const int p = m * B_ + b;
    const size_t off = (size_t)p * (N_*D_)
        + (size_t)((r >> 4) * 4 + (k >> 5)) * 512
        + (size_t)((r & 15) + ((k >> 3) & 3) * 16) * 8;
    *(short8*)&H[off] = *(short8*)h8;
    *(short8*)&L[off] = *(short8*)l8;

    s += __shfl_xor(s, 1); s += __shfl_xor(s, 2); s += __shfl_xor(s, 4); s += __shfl_xor(s, 8);
    s = fmaxf(s, __shfl_xor(s, 16)); s = fmaxf(s, __shfl_xor(s, 32));
    __shared__ float wm[4];
    if ((t & 63) == 0) wm[t >> 6] = s;
    __syncthreads();
    if (t == 0) {
        float mx = fmaxf(fmaxf(wm[0], wm[1]), fmaxf(wm[2], wm[3]));
        atomicMax(&Ru[p], __float_as_uint(mx));   // positive: uint order == float order
    }
}

// HIST: hh-only GEMM + direct global 64K-bin histogram (weight w).
// Low bits of blockIdx carry p so each pair's panel stays in one XCD L2.
__global__ __launch_bounds__(256) void hist_kernel(
    const ushort* __restrict__ H, const ushort* __restrict__ L,
    const uint32_t* __restrict__ Ru, uint32_t* __restrict__ hist)
{
    const int t = threadIdx.x;
    const int id = blockIdx.x;
    const int p = id & 15, tile = id >> 4;

    int rem = tile, ti = 0;
    while (true) { int len = NT - ti; if (rem < len) break; rem -= len; ++ti; }
    const int tj = ti + rem;
    const uint32_t w = (ti == tj) ? 1u : 2u;

    f32x4 acc[4][4];
    gemm_tile<false>(H + (size_t)p * (N_*D_), L, ti, tj, acc, t);

    const float R = __uint_as_float(Ru[p]);
    const float scl = (float)NBIN2 / (2.0f * R);
    uint32_t* gh = hist + (size_t)p * NBIN2;
    #pragma unroll
    for (int mm = 0; mm < 4; ++mm)
        #pragma unroll
        for (int nn = 0; nn < 4; ++nn)
            #pragma unroll
            for (int r = 0; r < 4; ++r) {
                int bin = (int)((acc[mm][nn][r] + R) * scl);
                if (bin < 0) bin = 0;
                if (bin >= NBIN2) bin = NBIN2 - 1;
                atomicAdd(&gh[bin], w);
            }
}

// descending scan over 64K bins: thr = lower edge of bin holding rank k
__global__ __launch_bounds__(256) void select_kernel(
    const uint32_t* __restrict__ hist, const int* __restrict__ kptr,
    const uint32_t* __restrict__ Ru, float* __restrict__ thr)
{
    const int p = blockIdx.x, t = threadIdx.x;
    const uint32_t* h = hist + (size_t)p * NBIN2;
    const uint32_t k0 = (uint32_t)kptr[0];
    const float R = __uint_as_float(Ru[p]);
    const float binw = 2.0f * R / (float)NBIN2;
    __shared__ uint32_t csum[256], cpre[256];
    const int top = NBIN2 - 1 - t * 256;
    uint32_t s = 0;
    for (int j = 0; j < 256; ++j) s += h[top - j];
    csum[t] = s;
    __syncthreads();
    if (t == 0) { uint32_t run = 0; for (int i = 0; i < 256; ++i) { cpre[i] = run; run += csum[i]; } }
    __syncthreads();
    const uint32_t above = cpre[t];
    if (above < k0 && above + s >= k0) {
        uint32_t cum = above;
        for (int j = 0; j < 256; ++j) {
            int bin = top - j;
            cum += h[bin];
            if (cum >= k0) { thr[p] = fmaf((float)bin, binw, -R); break; }
        }
    }
}

// MSE: full-precision GEMM for both matrices, masked squared diff -> double atomic
__global__ __launch_bounds__(256) void mse_kernel(
    const ushort* __restrict__ H, const ushort* __restrict__ L,
    const float* __restrict__ thr, double* __restrict__ accum)
{
    const int t = threadIdx.x;
    const int id = blockIdx.x;
    const int p = id & 7, tile = id >> 3;

    int rem = tile, ti = 0;
    while (true) { int len = NT - ti; if (rem < len) break; rem -= len; ++ti; }
    const int tj = ti + rem;
    const uint32_t w = (ti == tj) ? 1u : 2u;

    f32x4 acc[4][4], accT[4][4];
    gemm_tile<true>(H + (size_t)p * (N_*D_),        L + (size_t)p * (N_*D_),        ti, tj, acc,  t);
    gemm_tile<true>(H + (size_t)(B_ + p) * (N_*D_), L + (size_t)(B_ + p) * (N_*D_), ti, tj, accT, t);

    const float thrI = thr[p], thrT = thr[B_ + p];
    float local = 0.f;
    #pragma unroll
    for (int mm = 0; mm < 4; ++mm)
        #pragma unroll
        for (int nn = 0; nn < 4; ++nn)
            #pragma unroll
            for (int r = 0; r < 4; ++r) {
                float vI = acc[mm][nn][r],  aI = (vI >= thrI) ? vI : 0.f;
                float vT = accT[mm][nn][r], aT = (vT >= thrT) ? vT : 0.f;
                float d = aI - aT;
                local += d * d;
            }
    local *= (float)w;
    #pragma unroll
    for (int off = 32; off; off >>= 1) local += __shfl_down(local, off);
    __shared__ float wsum[4];
    if ((t & 63) == 0) wsum[t >> 6] = local;
    __syncthreads();
    if (t == 0) {
        double s2 = (double)wsum[0] + (double)wsum[1] + (double)wsum[2] + (double)wsum[3];
        atomicAdd(accum, s2);
    }
}

__global__ void finalize_kernel(const double* __restrict__ accum, float* __restrict__ out) {
    out[0] = (float)(accum[0] / ((double)B_ * (double)N_ * (double)N_));
}

extern "C" void kernel_launch(void* const* d_in, const int* in_sizes, int n_in,
                              void* d_out, int out_size, void* d_ws, size_t ws_size,
                              hipStream_t stream)
{
    const float* Xin = (const float*)d_in[0];
    const float* Xtg = (const float*)d_in[1];
    const int*  kptr = (const int*)d_in[3];
    float* out = (float*)d_out;

    char* ws = (char*)d_ws;
    double*   accum = (double*)  (ws + OFF_ACCUM);
    uint32_t* Ru    = (uint32_t*)(ws + OFF_RU);
    float*    thr   = (float*)   (ws + OFF_THR);
    uint32_t* hist  = (uint32_t*)(ws + OFF_HIST);
    ushort*   H     = (ushort*)  (ws + OFF_H);
    ushort*   L     = (ushort*)  (ws + OFF_L);
    if (ws_size < NEED) return;

    hipMemsetAsync(d_ws, 0, OFF_END, stream);   // accum, Ru, thr, hist

    dim3 blk(256);
    convert_kernel<<<dim3(1024, 2), blk, 0, stream>>>(Xin, Xtg, H, L, Ru);
    hist_kernel<<<dim3(NPAIRS * 16), blk, 0, stream>>>(H, L, Ru, hist);
    select_kernel<<<dim3(16), blk, 0, stream>>>(hist, kptr, Ru, thr);
    mse_kernel<<<dim3(NPAIRS * 8), blk, 0, stream>>>(H, L, thr, accum);
    finalize_kernel<<<1, 1, 0, stream>>>(accum, out);
}

// Round 7
// 181.847 us; speedup vs baseline: 7.6412x; 7.6412x over previous
//
#include <hip/hip_runtime.h>
#include <stdint.h>

#define N_ 2048
#define D_ 128
#define B_ 8
#define NT 16            // N_/128
#define NPAIRS 136       // NT*(NT+1)/2
#define NBINS 16384
#define GH 17            // hist block-groups per pair
#define TPG 8            // tiles per hist block (GH*TPG == NPAIRS)

typedef __attribute__((ext_vector_type(8))) _Float16 half8;
typedef __attribute__((ext_vector_type(4))) float f32x4;

// ws layout (bytes)
#define OFF_ACCUM 0
#define OFF_RU    256                            // 16 entries, 64B stride
#define OFF_THR   1280                           // 16 floats
#define OFF_REP   4096                           // 16*17*32768 = 8,912,896
#define OFF_F     (4096 + (size_t)16*GH*32768)   // 16 panels * 2048*128*2B = 8 MB
#define NEED      (OFF_F + (size_t)16*N_*D_*2)   // ~17.3 MB

// Fragment-major f16 panel: panel p (2048 rows x 128 k) as [128 rt][4 kt]
// 1KB fragments; within a fragment lane l=(r&15)+((k>>3)&3)*16 owns 16B at l*16.

// 128x128 tile (ti,tj) of X*X^T in f16 MFMA, direct-from-global fragments,
// double-buffered prefetch. 4 waves (2x2), each 64x64 = 4x4 frags of 16x16x32.
__device__ __forceinline__ void gemm16(const _Float16* __restrict__ Fp,
        int ti, int tj, f32x4 acc[4][4], int t)
{
    const int lane = t & 63;
    const int wv = t >> 6, wr = wv >> 1, wc = wv & 1;
    const _Float16* A  = Fp + (size_t)(ti*8 + wr*4)*2048 + (size_t)lane*8;
    const _Float16* Bp = Fp + (size_t)(tj*8 + wc*4)*2048 + (size_t)lane*8;

    half8 a[2][4], b[2][4];
    #pragma unroll
    for (int mm = 0; mm < 4; ++mm) {
        a[0][mm] = *(const half8*)&A[mm*2048];
        b[0][mm] = *(const half8*)&Bp[mm*2048];
    }
    #pragma unroll
    for (int mm = 0; mm < 4; ++mm)
        #pragma unroll
        for (int nn = 0; nn < 4; ++nn)
            acc[mm][nn] = f32x4{0.f, 0.f, 0.f, 0.f};

    #pragma unroll
    for (int kt = 0; kt < 4; ++kt) {
        const int cur = kt & 1, nxt = cur ^ 1;
        if (kt < 3) {
            #pragma unroll
            for (int mm = 0; mm < 4; ++mm) {
                a[nxt][mm] = *(const half8*)&A[mm*2048 + (kt+1)*512];
                b[nxt][mm] = *(const half8*)&Bp[mm*2048 + (kt+1)*512];
            }
        }
        #pragma unroll
        for (int mm = 0; mm < 4; ++mm)
            #pragma unroll
            for (int nn = 0; nn < 4; ++nn)
                acc[mm][nn] = __builtin_amdgcn_mfma_f32_16x16x32_f16(a[cur][mm], b[cur][nn], acc[mm][nn], 0, 0, 0);
    }
}

// f32 -> f16 fragment-major panels + fused per-pair max row-norm^2 (sim bound)
__global__ __launch_bounds__(256) void convert_kernel(
    const float* __restrict__ Xin, const float* __restrict__ Xtg,
    _Float16* __restrict__ F, uint32_t* __restrict__ Ru)
{
    const int t = threadIdx.x;
    const int m = blockIdx.y;
    const float* X = m ? Xtg : Xin;
    const size_t e8 = (size_t)blockIdx.x * 256 + t;
    const size_t idx = e8 * 8;
    const int b = (int)(e8 >> 15);
    const int r = (int)((idx >> 7) & 2047);
    const int k = (int)(idx & 127);

    float4 v0 = *(const float4*)&X[idx];
    float4 v1 = *(const float4*)&X[idx + 4];
    float vv[8] = {v0.x, v0.y, v0.z, v0.w, v1.x, v1.y, v1.z, v1.w};
    _Float16 h8[8];
    float s = 0.f;
    #pragma unroll
    for (int j = 0; j < 8; ++j) {
        float f = fminf(fmaxf(vv[j], -60000.f), 60000.f);  // f16-range guard
        h8[j] = (_Float16)f;
        s += vv[j] * vv[j];
    }
    const int p = m * B_ + b;
    const size_t off = (size_t)p * (N_*D_)
        + (size_t)((r >> 4) * 4 + (k >> 5)) * 512
        + (size_t)((r & 15) + ((k >> 3) & 3) * 16) * 8;
    *(half8*)&F[off] = *(half8*)h8;

    // 16 consecutive lanes cover one row of 128 k
    s += __shfl_xor(s, 1); s += __shfl_xor(s, 2); s += __shfl_xor(s, 4); s += __shfl_xor(s, 8);
    s = fmaxf(s, __shfl_xor(s, 16)); s = fmaxf(s, __shfl_xor(s, 32));
    __shared__ float wm[4];
    if ((t & 63) == 0) wm[t >> 6] = s;
    __syncthreads();
    if (t == 0) {
        float mx = fmaxf(fmaxf(wm[0], wm[1]), fmaxf(wm[2], wm[3]));
        atomicMax(&Ru[p * 16], __float_as_uint(mx));   // positive: uint order == float order
    }
}

// 16K-bin hist over [0,R] in packed-u16 LDS, 8 tiles/block, non-atomic
// replica flush. Low 4 bits of blockIdx carry p -> pair pinned to one XCD L2.
__global__ __launch_bounds__(256) void hist_kernel(
    const _Float16* __restrict__ F, const uint32_t* __restrict__ Ru,
    uint32_t* __restrict__ rep)
{
    __shared__ uint32_t lh[NBINS / 2];   // 32 KB packed u16 pairs
    const int t = threadIdx.x;
    const int id = blockIdx.x;
    const int p = id & 15, g = id >> 4;

    for (int i = t; i < NBINS/2; i += 256) lh[i] = 0;
    __syncthreads();

    const _Float16* Fp = F + (size_t)p * (N_*D_);
    const float R = __uint_as_float(Ru[p * 16]);
    const float scl = (float)NBINS / R;

    for (int j = 0; j < TPG; ++j) {
        int rem = g * TPG + j, ti = 0;
        while (true) { int len = NT - ti; if (rem < len) break; rem -= len; ++ti; }
        const int tj = ti + rem;
        const uint32_t w = (ti == tj) ? 1u : 2u;

        f32x4 acc[4][4];
        gemm16(Fp, ti, tj, acc, t);
        #pragma unroll
        for (int mm = 0; mm < 4; ++mm)
            #pragma unroll
            for (int nn = 0; nn < 4; ++nn)
                #pragma unroll
                for (int r = 0; r < 4; ++r) {
                    int bin = (int)(acc[mm][nn][r] * scl);   // negatives -> <0
                    if (bin < 0) bin = 0;                    // clamp: all v<=0 in bin 0
                    if (bin >= NBINS) bin = NBINS - 1;
                    atomicAdd(&lh[bin >> 1], w << ((bin & 1) * 16));
                }
    }
    __syncthreads();
    uint32_t* dst = rep + ((size_t)p * GH + g) * (NBINS/2);
    for (int i = t; i < NBINS/2; i += 256) dst[i] = lh[i];
}

// sum 17 replicas -> full u32 hist in LDS -> descending scan -> thr[p]
__global__ __launch_bounds__(256) void reduce_select(
    const uint32_t* __restrict__ rep, const int* __restrict__ kptr,
    const uint32_t* __restrict__ Ru, float* __restrict__ thr)
{
    __shared__ uint32_t h[NBINS];        // 64 KB
    __shared__ uint32_t csum[256], cpre[256];
    const int p = blockIdx.x, t = threadIdx.x;
    const uint32_t* base = rep + (size_t)p * GH * (NBINS/2);

    for (int j = 0; j < 32; ++j) {       // 8192 words / 256 threads
        const int wd = j * 256 + t;
        uint32_t lo = 0, hi = 0;
        #pragma unroll
        for (int g = 0; g < GH; ++g) {
            uint32_t x = base[(size_t)g * (NBINS/2) + wd];
            lo += x & 0xffffu; hi += x >> 16;
        }
        h[wd*2] = lo; h[wd*2 + 1] = hi;
    }
    __syncthreads();

    const uint32_t k0 = (uint32_t)kptr[0];
    const float R = __uint_as_float(Ru[p * 16]);
    const float binw = R / (float)NBINS;

    const int top = NBINS - 1 - t * 64;
    uint32_t s = 0;
    for (int j = 0; j < 64; ++j) s += h[top - j];
    csum[t] = s;
    __syncthreads();
    if (t == 0) { uint32_t run = 0; for (int i = 0; i < 256; ++i) { cpre[i] = run; run += csum[i]; } }
    __syncthreads();
    const uint32_t above = cpre[t];
    if (above < k0 && above + s >= k0) {
        uint32_t cum = above;
        for (int j = 0; j < 64; ++j) {
            int bin = top - j;
            cum += h[bin];
            if (cum >= k0) { thr[p] = (float)bin * binw; break; }   // lower edge
        }
    }
}

// masked MSE: f16 gemms for both matrices, squared diff -> double atomic.
// Low 3 bits of blockIdx carry p -> pair-group (Fin_p + Ftg_p = 2MB) on one XCD.
__global__ __launch_bounds__(256) void mse_kernel(
    const _Float16* __restrict__ F, const float* __restrict__ thr,
    double* __restrict__ accum)
{
    const int t = threadIdx.x;
    const int id = blockIdx.x;
    const int p = id & 7, tile = id >> 3;

    int rem = tile, ti = 0;
    while (true) { int len = NT - ti; if (rem < len) break; rem -= len; ++ti; }
    const int tj = ti + rem;
    const uint32_t w = (ti == tj) ? 1u : 2u;

    f32x4 acc[4][4], accT[4][4];
    gemm16(F + (size_t)p * (N_*D_),        ti, tj, acc,  t);
    gemm16(F + (size_t)(B_ + p) * (N_*D_), ti, tj, accT, t);

    const float thrI = thr[p], thrT = thr[B_ + p];
    float local = 0.f;
    #pragma unroll
    for (int mm = 0; mm < 4; ++mm)
        #pragma unroll
        for (int nn = 0; nn < 4; ++nn)
            #pragma unroll
            for (int r = 0; r < 4; ++r) {
                float vI = acc[mm][nn][r],  aI = (vI >= thrI) ? vI : 0.f;
                float vT = accT[mm][nn][r], aT = (vT >= thrT) ? vT : 0.f;
                float d = aI - aT;
                local += d * d;
            }
    local *= (float)w;
    #pragma unroll
    for (int off = 32; off; off >>= 1) local += __shfl_down(local, off);
    __shared__ float wsum[4];
    if ((t & 63) == 0) wsum[t >> 6] = local;
    __syncthreads();
    if (t == 0) {
        double s2 = (double)wsum[0] + (double)wsum[1] + (double)wsum[2] + (double)wsum[3];
        atomicAdd(accum, s2);
    }
}

__global__ void finalize_kernel(const double* __restrict__ accum, float* __restrict__ out) {
    out[0] = (float)(accum[0] / ((double)B_ * (double)N_ * (double)N_));
}

extern "C" void kernel_launch(void* const* d_in, const int* in_sizes, int n_in,
                              void* d_out, int out_size, void* d_ws, size_t ws_size,
                              hipStream_t stream)
{
    const float* Xin = (const float*)d_in[0];
    const float* Xtg = (const float*)d_in[1];
    const int*  kptr = (const int*)d_in[3];
    float* out = (float*)d_out;

    char* ws = (char*)d_ws;
    double*    accum = (double*)   (ws + OFF_ACCUM);
    uint32_t*  Ru    = (uint32_t*) (ws + OFF_RU);
    float*     thr   = (float*)    (ws + OFF_THR);
    uint32_t*  rep   = (uint32_t*) (ws + OFF_REP);
    _Float16*  F     = (_Float16*) (ws + OFF_F);
    if (ws_size < NEED) return;

    hipMemsetAsync(d_ws, 0, OFF_REP, stream);   // accum, Ru, thr (replicas/F fully overwritten)

    dim3 blk(256);
    convert_kernel<<<dim3(1024, 2), blk, 0, stream>>>(Xin, Xtg, F, Ru);
    hist_kernel<<<dim3(GH * 16), blk, 0, stream>>>(F, Ru, rep);
    reduce_select<<<dim3(16), blk, 0, stream>>>(rep, kptr, Ru, thr);
    mse_kernel<<<dim3(NPAIRS * 8), blk, 0, stream>>>(F, thr, accum);
    finalize_kernel<<<1, 1, 0, stream>>>(accum, out);
}